// Round 8
// baseline (255.237 us; speedup 1.0000x reference)
//
#include <hip/hip_runtime.h>
#include <hip/hip_bf16.h>

#define B_   8
#define C_   256
#define CQ_  32
#define N_   4096
#define OC_  320   // stacked output channels: q 0..31 | k 32..63 | v 64..319

typedef __bf16 bf16;
typedef __attribute__((ext_vector_type(8))) __bf16 bf16x8;
typedef __attribute__((ext_vector_type(4))) __bf16 bf16x4;
typedef __attribute__((ext_vector_type(4))) float f32x4;

#define LOG2E 1.4426950408889634f

// ws layout (bf16 element offsets):
//   qT [B][N][CQ] | kT [B][N][CQ] | vb [B][C][N] | Wb [320][256] | xT [B][N][C]
//   then fp32 bias[320] at byte offset BIAS_BYTE.
#define QT_OFF ((size_t)0)
#define KT_OFF ((size_t)B_*N_*CQ_)
#define VB_OFF ((size_t)2*B_*N_*CQ_)
#define WB_OFF (VB_OFF + (size_t)B_*C_*N_)
#define XT_OFF (WB_OFF + (size_t)OC_*C_)
#define WS_END_BF16 (XT_OFF + (size_t)B_*N_*C_)
#define BIAS_BYTE (WS_END_BF16*2)
#define WS_BYTES (BIAS_BYTE + OC_*4)

// exp2 via builtin (compiler-visible TRANS op; hazards handled).
__device__ inline float exp2_hw(float x) {
  return __builtin_amdgcn_exp2f(x);
}

// Raw barrier: LDS fence only. Global loads stay IN FLIGHT across it
// (unlike __syncthreads, which drains vmcnt(0) and kills prefetch).
__device__ inline void bar_lds() {
  asm volatile("s_waitcnt lgkmcnt(0)" ::: "memory");
  __builtin_amdgcn_s_barrier();
}

// ---------------------------------------------------------------------------
// prep_w: stack Wq|Wk|Wv -> bf16 Wb[320][256], biases -> fp32[320].
// ---------------------------------------------------------------------------
__global__ __launch_bounds__(256) void prep_w(
    const float* __restrict__ Wq, const float* __restrict__ bq,
    const float* __restrict__ Wk, const float* __restrict__ bk,
    const float* __restrict__ Wv, const float* __restrict__ bv,
    bf16* __restrict__ ws)
{
  const int idx = blockIdx.x*256 + threadIdx.x;      // 0..81919
  const int o = idx >> 8, c = idx & 255;
  const float v = (o < 32) ? Wq[o*C_ + c]
                : (o < 64) ? Wk[(o-32)*C_ + c]
                           : Wv[(o-64)*C_ + c];
  ws[WB_OFF + idx] = (bf16)v;
  if (idx < OC_) {
    const float bb = (idx < 32) ? bq[idx] : (idx < 64) ? bk[idx-32] : bv[idx-64];
    ((float*)((char*)ws + BIAS_BYTE))[idx] = bb;
  }
}

// ---------------------------------------------------------------------------
// prep_x: x fp32 [B][C][N] -> bf16 xT [B][N][C] (B-frag layout, contiguous c).
// ---------------------------------------------------------------------------
__global__ __launch_bounds__(256) void prep_x(
    const float* __restrict__ x, bf16* __restrict__ ws)
{
  const int b  = blockIdx.z;
  const int n  = blockIdx.x*64 + (threadIdx.x & 63);
  const int c0 = blockIdx.y*32 + (threadIdx.x >> 6)*8;
  const float* xp = x + ((size_t)b*C_ + c0)*N_ + n;
  bf16x8 pk;
  #pragma unroll
  for (int j = 0; j < 8; ++j) pk[j] = (bf16)xp[(size_t)j*N_];
  *(bf16x8*)(ws + XT_OFF + ((size_t)b*N_ + n)*C_ + c0) = pk;
}

// ---------------------------------------------------------------------------
// qkv_mfma: D[o][n] = sum_c Wb[o][c] xT[n][c] + bias[o]. Per block: 320 o x
// 64 n. 4 waves; wave w owns 5 o-tiles. K=256 in 8 MFMA steps, no LDS.
// q outputs pre-scaled by LOG2E so attention uses raw 2^x.
// ---------------------------------------------------------------------------
__global__ __launch_bounds__(256) void qkv_mfma(
    const bf16* __restrict__ wsc, bf16* __restrict__ ws)
{
  const int b   = blockIdx.y;
  const int n0  = blockIdx.x * 64;
  const int tid = threadIdx.x, lane = tid & 63;
  const int w   = __builtin_amdgcn_readfirstlane(tid >> 6);
  const int lm  = lane & 15, g = lane >> 4;
  const int obase = w*80;

  const bf16*  Wb   = wsc + WB_OFF;
  const bf16*  xT   = wsc + XT_OFF + (size_t)b*N_*C_;
  const float* bias = (const float*)((const char*)wsc + BIAS_BYTE);

  f32x4 acc[5][4];
  #pragma unroll
  for (int ot = 0; ot < 5; ++ot)
    #pragma unroll
    for (int nt = 0; nt < 4; ++nt)
      acc[ot][nt] = (f32x4){0.f, 0.f, 0.f, 0.f};

  for (int kk = 0; kk < 8; ++kk) {
    bf16x8 wa[5], xf[4];
    #pragma unroll
    for (int ot = 0; ot < 5; ++ot)
      wa[ot] = *(const bf16x8*)(Wb + (size_t)(obase + ot*16 + lm)*C_ + kk*32 + g*8);
    #pragma unroll
    for (int nt = 0; nt < 4; ++nt)
      xf[nt] = *(const bf16x8*)(xT + (size_t)(n0 + nt*16 + lm)*C_ + kk*32 + g*8);
    #pragma unroll
    for (int ot = 0; ot < 5; ++ot)
      #pragma unroll
      for (int nt = 0; nt < 4; ++nt)
        acc[ot][nt] = __builtin_amdgcn_mfma_f32_16x16x32_bf16(
                        wa[ot], xf[nt], acc[ot][nt], 0, 0, 0);
  }

  float bv4[5][4];
  #pragma unroll
  for (int ot = 0; ot < 5; ++ot)
    #pragma unroll
    for (int r = 0; r < 4; ++r)
      bv4[ot][r] = bias[obase + ot*16 + g*4 + r];

  bf16* qT = ws + QT_OFF + (size_t)b*N_*CQ_;
  bf16* kT = ws + KT_OFF + (size_t)b*N_*CQ_;
  bf16* vb = ws + VB_OFF + (size_t)b*C_*N_;

  #pragma unroll
  for (int ot = 0; ot < 5; ++ot) {
    const int O = obase + ot*16;
    #pragma unroll
    for (int nt = 0; nt < 4; ++nt) {
      const int n = n0 + nt*16 + lm;
      if (O < 32) {
        bf16x4 pk;   // q: fold log2(e)
        #pragma unroll
        for (int r = 0; r < 4; ++r)
          pk[r] = (bf16)((acc[ot][nt][r] + bv4[ot][r]) * LOG2E);
        *(bf16x4*)(qT + (size_t)n*CQ_ + O + g*4) = pk;
      } else if (O < 64) {
        bf16x4 pk;
        #pragma unroll
        for (int r = 0; r < 4; ++r) pk[r] = (bf16)(acc[ot][nt][r] + bv4[ot][r]);
        *(bf16x4*)(kT + (size_t)n*CQ_ + (O - 32) + g*4) = pk;
      } else {
        #pragma unroll
        for (int r = 0; r < 4; ++r)
          vb[(size_t)(O - 64 + g*4 + r)*N_ + n] = (bf16)(acc[ot][nt][r] + bv4[ot][r]);
      }
    }
  }
}

// ---------------------------------------------------------------------------
// attn_kernel v4: raw-barrier pipeline (T3/T4/T5).
// 8 waves / 512 threads, n-tile 128, 512 blocks (2/CU).
// Per tile: QK^T (q prefetched last tile) -> exp2 -> swizzled LDS P write ->
// issue NEXT tile's q + kc0,1 v-frags (stay in flight across the RAW barrier)
// -> lgkmcnt(0) + s_barrier (no vmcnt drain!) -> issue this tile's kc2,3
// v-frags -> setprio(1) PV 32 MFMAs setprio(0).
// WAR on the P double-buffer is safe: a wave's reads of buf X are consumed
// (lgkm-waited) by its PV MFMAs before it reaches the next barrier, and the
// overwrite of X sits behind that barrier.
// ---------------------------------------------------------------------------
#define TILE_BODY(T, QF, VF, QN, VN, PBUF)                                    \
  {                                                                           \
    f32x4 s[4];                                                               \
    _Pragma("unroll")                                                         \
    for (int ms = 0; ms < 4; ++ms)                                            \
      s[ms] = __builtin_amdgcn_mfma_f32_16x16x32_bf16(QF, kb[ms], zero4, 0, 0, 0); \
    _Pragma("unroll")                                                         \
    for (int ms = 0; ms < 4; ++ms) {                                          \
      float p0 = exp2_hw(s[ms][0]);                                           \
      float p1 = exp2_hw(s[ms][1]);                                           \
      float p2 = exp2_hw(s[ms][2]);                                           \
      float p3 = exp2_hw(s[ms][3]);                                           \
      colsum[ms] += (p0 + p1) + (p2 + p3);                                    \
      bf16x4 pk;                                                              \
      pk[0] = (bf16)p0; pk[1] = (bf16)p1; pk[2] = (bf16)p2; pk[3] = (bf16)p3; \
      const int m = lm + 16*ms;                                               \
      *(bf16x4*)((PBUF) + m*256 + (swb ^ ((m & 7) << 4))) = pk;               \
    }                                                                         \
    /* next tile q + kc0,1 v: in flight across the raw barrier */             \
    {                                                                         \
      const size_t pn = (size_t)(((T) + 1) & 31) * 128;                       \
      QN = *(const bf16x8*)(qp + pn*CQ_);                                     \
      _Pragma("unroll")                                                       \
      for (int cs = 0; cs < 2; ++cs)                                          \
        _Pragma("unroll")                                                     \
        for (int kc = 0; kc < 2; ++kc)                                        \
          VN[cs][kc] = *(const bf16x8*)(vp0 + (size_t)cs*16*N_ + pn + kc*32); \
    }                                                                         \
    bar_lds();                                                                \
    /* this tile's kc2,3 v: consumed after 16 MFMAs (~300 cy cover) */        \
    bf16x8 vfC[2][2];                                                         \
    _Pragma("unroll")                                                         \
    for (int cs = 0; cs < 2; ++cs)                                            \
      _Pragma("unroll")                                                       \
      for (int kc = 0; kc < 2; ++kc)                                          \
        vfC[cs][kc] = *(const bf16x8*)(vp0 + (size_t)cs*16*N_                 \
                                       + (size_t)(T)*128 + 64 + kc*32);       \
    __builtin_amdgcn_s_setprio(1);                                            \
    _Pragma("unroll")                                                         \
    for (int kc = 0; kc < 4; ++kc)                                            \
      _Pragma("unroll")                                                       \
      for (int ms = 0; ms < 4; ++ms) {                                        \
        const int m = lm + 16*ms;                                             \
        bf16x8 pf = *(const bf16x8*)((PBUF) + m*256                           \
                                     + ((kc*64 + g*16) ^ ((m & 7) << 4)));    \
        _Pragma("unroll")                                                     \
        for (int cs = 0; cs < 2; ++cs)                                        \
          acc[cs][ms] = __builtin_amdgcn_mfma_f32_16x16x32_bf16(              \
                          (kc < 2) ? VF[cs][kc] : vfC[cs][kc-2],              \
                          pf, acc[cs][ms], 0, 0, 0);                          \
      }                                                                       \
    __builtin_amdgcn_s_setprio(0);                                            \
  }

__global__ __launch_bounds__(512, 4) void attn_kernel(
    const bf16* __restrict__ ws, const float* __restrict__ x,
    const float* __restrict__ gamma, float* __restrict__ out)
{
  const int bid  = blockIdx.x;
  const int b    = bid & 7;
  const int m0   = (bid >> 3) << 6;
  const int tid  = threadIdx.x;
  const int lane = tid & 63;
  const int w    = __builtin_amdgcn_readfirstlane(tid >> 6);   // 0..7
  const int lm   = lane & 15;
  const int g    = lane >> 4;

  const bf16* qT = ws + QT_OFF + (size_t)b*N_*CQ_;
  const bf16* kT = ws + KT_OFF + (size_t)b*N_*CQ_;
  const bf16* vb = ws + VB_OFF + (size_t)b*C_*N_;

  __shared__ __align__(16) char Pb[2][64*256]; // [buf][m][256B swizzled row]
  __shared__ float red[8][64];
  __shared__ float dsh[64];

  // k B-frags for the block's 64 columns (constant over loop)
  bf16x8 kb[4];
  #pragma unroll
  for (int ms = 0; ms < 4; ++ms)
    kb[ms] = *(const bf16x8*)(kT + (size_t)(m0 + ms*16 + lm)*CQ_ + g*8);

  f32x4 acc[2][4];                 // [c-subtile][m-subtile]
  #pragma unroll
  for (int cs = 0; cs < 2; ++cs)
    #pragma unroll
    for (int ms = 0; ms < 4; ++ms)
      acc[cs][ms] = (f32x4){0.f, 0.f, 0.f, 0.f};
  float colsum[4] = {0.f, 0.f, 0.f, 0.f};

  const int c0  = w*32;            // PV c-range
  const int swb = w*32 + g*8;      // P-write byte base, pre-XOR
  const f32x4 zero4 = (f32x4){0.f, 0.f, 0.f, 0.f};

  // per-wave source pointers
  const bf16* qp  = qT + (size_t)(w*16 + lm)*CQ_ + g*8;   // + n0*CQ_
  const bf16* vp0 = vb + (size_t)(c0 + lm)*N_ + g*8;      // + cs*16*N_ + n

  // prologue: prefetch tile 0 (q + kc0,1 v-frags)
  bf16x8 qfA = *(const bf16x8*)(qp);
  bf16x8 vfA[2][2];
  #pragma unroll
  for (int cs = 0; cs < 2; ++cs)
    #pragma unroll
    for (int kc = 0; kc < 2; ++kc)
      vfA[cs][kc] = *(const bf16x8*)(vp0 + (size_t)cs*16*N_ + kc*32);
  bf16x8 qfB;
  bf16x8 vfB[2][2];

  for (int tt = 0; tt < 16; ++tt) {
    const int t0 = 2*tt;
    TILE_BODY(t0,     qfA, vfA, qfB, vfB, Pb[0]);
    TILE_BODY(t0 + 1, qfB, vfB, qfA, vfA, Pb[1]);
  }

  // ---- denominators: reduce colsum over lane-groups then 8 waves ----
  #pragma unroll
  for (int ms = 0; ms < 4; ++ms) {
    colsum[ms] += __shfl_xor(colsum[ms], 16, 64);
    colsum[ms] += __shfl_xor(colsum[ms], 32, 64);
  }
  if (lane < 16) {
    #pragma unroll
    for (int ms = 0; ms < 4; ++ms) red[w][lm + 16*ms] = colsum[ms];
  }
  __syncthreads();
  if (tid < 64) {
    float sden = 0.f;
    #pragma unroll
    for (int r2 = 0; r2 < 8; ++r2) sden += red[r2][tid];
    dsh[tid] = sden;
  }
  __syncthreads();

  // ---- epilogue: out = gamma*O/denom + x ----
  const float gam = gamma[0];
  float inv[4];
  #pragma unroll
  for (int ms = 0; ms < 4; ++ms) inv[ms] = gam / dsh[lm + 16*ms];

  #pragma unroll
  for (int cs = 0; cs < 2; ++cs)
    #pragma unroll
    for (int ms = 0; ms < 4; ++ms)
      #pragma unroll
      for (int r = 0; r < 4; ++r) {
        const int c = c0 + cs*16 + g*4 + r;
        const int m = m0 + 16*ms + lm;
        const size_t idx = ((size_t)b*C_ + c)*N_ + m;
        out[idx] = acc[cs][ms][r] * inv[ms] + x[idx];
      }
}

extern "C" void kernel_launch(void* const* d_in, const int* in_sizes, int n_in,
                              void* d_out, int out_size, void* d_ws, size_t ws_size,
                              hipStream_t stream) {
  const float* x     = (const float*)d_in[0];
  const float* Wq    = (const float*)d_in[1];
  const float* bq    = (const float*)d_in[2];
  const float* Wk    = (const float*)d_in[3];
  const float* bk    = (const float*)d_in[4];
  const float* Wv    = (const float*)d_in[5];
  const float* bv    = (const float*)d_in[6];
  const float* gamma = (const float*)d_in[7];
  float* out = (float*)d_out;
  bf16* ws   = (bf16*)d_ws;

  if (ws_size < WS_BYTES) return;   // ~37.9 MB scratch

  prep_w<<<320, 256, 0, stream>>>(Wq, bq, Wk, bk, Wv, bv, ws);
  prep_x<<<dim3(64, 8, 8), 256, 0, stream>>>(x, ws);
  qkv_mfma<<<dim3(64, 8), 256, 0, stream>>>(ws, ws);
  attn_kernel<<<512, 512, 0, stream>>>(ws, x, gamma, out);
}

// Round 9
// 202.016 us; speedup vs baseline: 1.2634x; 1.2634x over previous
//
#include <hip/hip_runtime.h>
#include <hip/hip_bf16.h>

#define B_   8
#define C_   256
#define CQ_  32
#define N_   4096
#define OC_  320   // stacked output channels: q 0..31 | k 32..63 | v 64..319

typedef __bf16 bf16;
typedef __attribute__((ext_vector_type(8))) __bf16 bf16x8;
typedef __attribute__((ext_vector_type(4))) __bf16 bf16x4;
typedef __attribute__((ext_vector_type(4))) float f32x4;

#define LOG2E 1.4426950408889634f

// ws layout (bf16 element offsets):
//   qT [B][N][CQ] | kT [B][N][CQ] | vb [B][C][N] | Wb [320][256] | xT [B][N][C]
//   then fp32 bias[320] at byte offset BIAS_BYTE.
#define QT_OFF ((size_t)0)
#define KT_OFF ((size_t)B_*N_*CQ_)
#define VB_OFF ((size_t)2*B_*N_*CQ_)
#define WB_OFF (VB_OFF + (size_t)B_*C_*N_)
#define XT_OFF (WB_OFF + (size_t)OC_*C_)
#define WS_END_BF16 (XT_OFF + (size_t)B_*N_*C_)
#define BIAS_BYTE (WS_END_BF16*2)
#define WS_BYTES (BIAS_BYTE + OC_*4)

// exp2 via builtin (compiler-visible TRANS op; hazards handled).
__device__ inline float exp2_hw(float x) {
  return __builtin_amdgcn_exp2f(x);
}

// ---------------------------------------------------------------------------
// prep_w: stack Wq|Wk|Wv -> bf16 Wb[320][256], biases -> fp32[320].
// ---------------------------------------------------------------------------
__global__ __launch_bounds__(256) void prep_w(
    const float* __restrict__ Wq, const float* __restrict__ bq,
    const float* __restrict__ Wk, const float* __restrict__ bk,
    const float* __restrict__ Wv, const float* __restrict__ bv,
    bf16* __restrict__ ws)
{
  const int idx = blockIdx.x*256 + threadIdx.x;      // 0..81919
  const int o = idx >> 8, c = idx & 255;
  const float v = (o < 32) ? Wq[o*C_ + c]
                : (o < 64) ? Wk[(o-32)*C_ + c]
                           : Wv[(o-64)*C_ + c];
  ws[WB_OFF + idx] = (bf16)v;
  if (idx < OC_) {
    const float bb = (idx < 32) ? bq[idx] : (idx < 64) ? bk[idx-32] : bv[idx-64];
    ((float*)((char*)ws + BIAS_BYTE))[idx] = bb;
  }
}

// ---------------------------------------------------------------------------
// prep_x: x fp32 [B][C][N] -> bf16 xT [B][N][C] (B-frag layout, contiguous c).
// ---------------------------------------------------------------------------
__global__ __launch_bounds__(256) void prep_x(
    const float* __restrict__ x, bf16* __restrict__ ws)
{
  const int b  = blockIdx.z;
  const int n  = blockIdx.x*64 + (threadIdx.x & 63);
  const int c0 = blockIdx.y*32 + (threadIdx.x >> 6)*8;
  const float* xp = x + ((size_t)b*C_ + c0)*N_ + n;
  bf16x8 pk;
  #pragma unroll
  for (int j = 0; j < 8; ++j) pk[j] = (bf16)xp[(size_t)j*N_];
  *(bf16x8*)(ws + XT_OFF + ((size_t)b*N_ + n)*C_ + c0) = pk;
}

// ---------------------------------------------------------------------------
// qkv_mfma: D[o][n] = sum_c Wb[o][c] xT[n][c] + bias[o]. Per block: 320 o x
// 64 n. 4 waves; wave w owns 5 o-tiles. K=256 in 8 MFMA steps, no LDS.
// q outputs pre-scaled by LOG2E so attention uses raw 2^x.
// ---------------------------------------------------------------------------
__global__ __launch_bounds__(256) void qkv_mfma(
    const bf16* __restrict__ wsc, bf16* __restrict__ ws)
{
  const int b   = blockIdx.y;
  const int n0  = blockIdx.x * 64;
  const int tid = threadIdx.x, lane = tid & 63;
  const int w   = __builtin_amdgcn_readfirstlane(tid >> 6);
  const int lm  = lane & 15, g = lane >> 4;
  const int obase = w*80;

  const bf16*  Wb   = wsc + WB_OFF;
  const bf16*  xT   = wsc + XT_OFF + (size_t)b*N_*C_;
  const float* bias = (const float*)((const char*)wsc + BIAS_BYTE);

  f32x4 acc[5][4];
  #pragma unroll
  for (int ot = 0; ot < 5; ++ot)
    #pragma unroll
    for (int nt = 0; nt < 4; ++nt)
      acc[ot][nt] = (f32x4){0.f, 0.f, 0.f, 0.f};

  for (int kk = 0; kk < 8; ++kk) {
    bf16x8 wa[5], xf[4];
    #pragma unroll
    for (int ot = 0; ot < 5; ++ot)
      wa[ot] = *(const bf16x8*)(Wb + (size_t)(obase + ot*16 + lm)*C_ + kk*32 + g*8);
    #pragma unroll
    for (int nt = 0; nt < 4; ++nt)
      xf[nt] = *(const bf16x8*)(xT + (size_t)(n0 + nt*16 + lm)*C_ + kk*32 + g*8);
    #pragma unroll
    for (int ot = 0; ot < 5; ++ot)
      #pragma unroll
      for (int nt = 0; nt < 4; ++nt)
        acc[ot][nt] = __builtin_amdgcn_mfma_f32_16x16x32_bf16(
                        wa[ot], xf[nt], acc[ot][nt], 0, 0, 0);
  }

  float bv4[5][4];
  #pragma unroll
  for (int ot = 0; ot < 5; ++ot)
    #pragma unroll
    for (int r = 0; r < 4; ++r)
      bv4[ot][r] = bias[obase + ot*16 + g*4 + r];

  bf16* qT = ws + QT_OFF + (size_t)b*N_*CQ_;
  bf16* kT = ws + KT_OFF + (size_t)b*N_*CQ_;
  bf16* vb = ws + VB_OFF + (size_t)b*C_*N_;

  #pragma unroll
  for (int ot = 0; ot < 5; ++ot) {
    const int O = obase + ot*16;
    #pragma unroll
    for (int nt = 0; nt < 4; ++nt) {
      const int n = n0 + nt*16 + lm;
      if (O < 32) {
        bf16x4 pk;   // q: fold log2(e)
        #pragma unroll
        for (int r = 0; r < 4; ++r)
          pk[r] = (bf16)((acc[ot][nt][r] + bv4[ot][r]) * LOG2E);
        *(bf16x4*)(qT + (size_t)n*CQ_ + O + g*4) = pk;
      } else if (O < 64) {
        bf16x4 pk;
        #pragma unroll
        for (int r = 0; r < 4; ++r) pk[r] = (bf16)(acc[ot][nt][r] + bv4[ot][r]);
        *(bf16x4*)(kT + (size_t)n*CQ_ + (O - 32) + g*4) = pk;
      } else {
        #pragma unroll
        for (int r = 0; r < 4; ++r)
          vb[(size_t)(O - 64 + g*4 + r)*N_ + n] = (bf16)(acc[ot][nt][r] + bv4[ot][r]);
      }
    }
  }
}

// ---------------------------------------------------------------------------
// attn_kernel v5: v2 structure + 2-tile phases + quad-buffered P.
// 8 waves / 512 threads, 512 blocks (2/CU), n-tile 128, 16 phases x 2 tiles.
// Per phase: issue q/vfA loads for BOTH tiles -> 2x QK^T (8 MFMAs, two
// independent chains) -> 2x exp2/pack/swizzled-P-write (distinct buffers)
// -> ONE __syncthreads -> PV 64 MFMAs (vfB loads interleaved mid-stream).
// Quad-buffer makes the single barrier WAR-safe: phase p writes pair p&1,
// while PV(p-1) read the other pair; rewrite of a pair happens one full
// barrier after its last read.
// No cross-barrier register pinning (v3/v4 spill lesson): the compiler may
// hoist next-phase loads above PV on its own, within its budget.
// ---------------------------------------------------------------------------
__global__ __launch_bounds__(512, 4) void attn_kernel(
    const bf16* __restrict__ ws, const float* __restrict__ x,
    const float* __restrict__ gamma, float* __restrict__ out)
{
  const int bid  = blockIdx.x;
  const int b    = bid & 7;
  const int m0   = (bid >> 3) << 6;
  const int tid  = threadIdx.x;
  const int lane = tid & 63;
  const int w    = __builtin_amdgcn_readfirstlane(tid >> 6);   // 0..7
  const int lm   = lane & 15;
  const int g    = lane >> 4;

  const bf16* qT = ws + QT_OFF + (size_t)b*N_*CQ_;
  const bf16* kT = ws + KT_OFF + (size_t)b*N_*CQ_;
  const bf16* vb = ws + VB_OFF + (size_t)b*C_*N_;

  __shared__ __align__(16) char Pb[4][64*256]; // 4 bufs: [m][256B swizzled]
  __shared__ float red[8][64];
  __shared__ float dsh[64];

  // k B-frags for the block's 64 columns (constant over loop)
  bf16x8 kb[4];
  #pragma unroll
  for (int ms = 0; ms < 4; ++ms)
    kb[ms] = *(const bf16x8*)(kT + (size_t)(m0 + ms*16 + lm)*CQ_ + g*8);

  f32x4 acc[2][4];                 // [c-subtile][m-subtile]
  #pragma unroll
  for (int cs = 0; cs < 2; ++cs)
    #pragma unroll
    for (int ms = 0; ms < 4; ++ms)
      acc[cs][ms] = (f32x4){0.f, 0.f, 0.f, 0.f};
  float colsum[4] = {0.f, 0.f, 0.f, 0.f};

  const int c0  = w*32;            // PV c-range
  const int swb = w*32 + g*8;      // P-write byte base, pre-XOR
  const f32x4 zero4 = (f32x4){0.f, 0.f, 0.f, 0.f};

  // per-wave source pointers
  const bf16* qp  = qT + (size_t)(w*16 + lm)*CQ_ + g*8;   // + n*CQ_
  const bf16* vp0 = vb + (size_t)(c0 + lm)*N_ + g*8;      // + cs*16*N_ + n

  for (int p = 0; p < 16; ++p) {
    const size_t n0 = (size_t)p * 256;
    const size_t n1 = n0 + 128;
    char* pb0 = Pb[(p & 1)*2 + 0];
    char* pb1 = Pb[(p & 1)*2 + 1];

    // ---- issue loads for both tiles (two independent QKT chains) ----
    bf16x8 qf0 = *(const bf16x8*)(qp + n0*CQ_);
    bf16x8 qf1 = *(const bf16x8*)(qp + n1*CQ_);
    bf16x8 vfA0[2][2], vfA1[2][2];
    #pragma unroll
    for (int cs = 0; cs < 2; ++cs)
      #pragma unroll
      for (int kc = 0; kc < 2; ++kc) {
        vfA0[cs][kc] = *(const bf16x8*)(vp0 + (size_t)cs*16*N_ + n0 + kc*32);
        vfA1[cs][kc] = *(const bf16x8*)(vp0 + (size_t)cs*16*N_ + n1 + kc*32);
      }

    // ---- QK^T both tiles ----
    f32x4 s0[4], s1[4];
    #pragma unroll
    for (int ms = 0; ms < 4; ++ms) {
      s0[ms] = __builtin_amdgcn_mfma_f32_16x16x32_bf16(qf0, kb[ms], zero4, 0, 0, 0);
      s1[ms] = __builtin_amdgcn_mfma_f32_16x16x32_bf16(qf1, kb[ms], zero4, 0, 0, 0);
    }

    // ---- exp2 / colsum / pack / swizzled P-writes (both buffers) ----
    #pragma unroll
    for (int ms = 0; ms < 4; ++ms) {
      const int m = lm + 16*ms;
      const int wo = m*256 + (swb ^ ((m & 7) << 4));
      float a0 = exp2_hw(s0[ms][0]), a1 = exp2_hw(s0[ms][1]);
      float a2 = exp2_hw(s0[ms][2]), a3 = exp2_hw(s0[ms][3]);
      float b0 = exp2_hw(s1[ms][0]), b1 = exp2_hw(s1[ms][1]);
      float b2 = exp2_hw(s1[ms][2]), b3 = exp2_hw(s1[ms][3]);
      colsum[ms] += ((a0 + a1) + (a2 + a3)) + ((b0 + b1) + (b2 + b3));
      bf16x4 pk0, pk1;
      pk0[0] = (bf16)a0; pk0[1] = (bf16)a1; pk0[2] = (bf16)a2; pk0[3] = (bf16)a3;
      pk1[0] = (bf16)b0; pk1[1] = (bf16)b1; pk1[2] = (bf16)b2; pk1[3] = (bf16)b3;
      *(bf16x4*)(pb0 + wo) = pk0;
      *(bf16x4*)(pb1 + wo) = pk1;
    }
    __syncthreads();               // P(p) visible; quad-buffer covers WAR

    // ---- PV: 64 MFMAs; vfB loads interleaved for latency cover ----
    bf16x8 vfB0[2][2];
    #pragma unroll
    for (int cs = 0; cs < 2; ++cs)
      #pragma unroll
      for (int kc = 0; kc < 2; ++kc)
        vfB0[cs][kc] = *(const bf16x8*)(vp0 + (size_t)cs*16*N_ + n0 + 64 + kc*32);

    // tile0 kc0,1 (vfA0 ready)
    #pragma unroll
    for (int kc = 0; kc < 2; ++kc)
      #pragma unroll
      for (int ms = 0; ms < 4; ++ms) {
        const int m = lm + 16*ms;
        bf16x8 pf = *(const bf16x8*)(pb0 + m*256 + ((kc*64 + g*16) ^ ((m & 7) << 4)));
        #pragma unroll
        for (int cs = 0; cs < 2; ++cs)
          acc[cs][ms] = __builtin_amdgcn_mfma_f32_16x16x32_bf16(
                          vfA0[cs][kc], pf, acc[cs][ms], 0, 0, 0);
      }

    bf16x8 vfB1[2][2];
    #pragma unroll
    for (int cs = 0; cs < 2; ++cs)
      #pragma unroll
      for (int kc = 0; kc < 2; ++kc)
        vfB1[cs][kc] = *(const bf16x8*)(vp0 + (size_t)cs*16*N_ + n1 + 64 + kc*32);

    // tile0 kc2,3 (vfB0: ~16 MFMAs of cover)
    #pragma unroll
    for (int kc = 0; kc < 2; ++kc)
      #pragma unroll
      for (int ms = 0; ms < 4; ++ms) {
        const int m = lm + 16*ms;
        bf16x8 pf = *(const bf16x8*)(pb0 + m*256 + (((kc+2)*64 + g*16) ^ ((m & 7) << 4)));
        #pragma unroll
        for (int cs = 0; cs < 2; ++cs)
          acc[cs][ms] = __builtin_amdgcn_mfma_f32_16x16x32_bf16(
                          vfB0[cs][kc], pf, acc[cs][ms], 0, 0, 0);
      }

    // tile1 kc0,1 (vfA1: issued at phase top)
    #pragma unroll
    for (int kc = 0; kc < 2; ++kc)
      #pragma unroll
      for (int ms = 0; ms < 4; ++ms) {
        const int m = lm + 16*ms;
        bf16x8 pf = *(const bf16x8*)(pb1 + m*256 + ((kc*64 + g*16) ^ ((m & 7) << 4)));
        #pragma unroll
        for (int cs = 0; cs < 2; ++cs)
          acc[cs][ms] = __builtin_amdgcn_mfma_f32_16x16x32_bf16(
                          vfA1[cs][kc], pf, acc[cs][ms], 0, 0, 0);
      }

    // tile1 kc2,3 (vfB1: ~32 MFMAs of cover)
    #pragma unroll
    for (int kc = 0; kc < 2; ++kc)
      #pragma unroll
      for (int ms = 0; ms < 4; ++ms) {
        const int m = lm + 16*ms;
        bf16x8 pf = *(const bf16x8*)(pb1 + m*256 + (((kc+2)*64 + g*16) ^ ((m & 7) << 4)));
        #pragma unroll
        for (int cs = 0; cs < 2; ++cs)
          acc[cs][ms] = __builtin_amdgcn_mfma_f32_16x16x32_bf16(
                          vfB1[cs][kc], pf, acc[cs][ms], 0, 0, 0);
      }
  }

  // ---- denominators: reduce colsum over lane-groups then 8 waves ----
  #pragma unroll
  for (int ms = 0; ms < 4; ++ms) {
    colsum[ms] += __shfl_xor(colsum[ms], 16, 64);
    colsum[ms] += __shfl_xor(colsum[ms], 32, 64);
  }
  if (lane < 16) {
    #pragma unroll
    for (int ms = 0; ms < 4; ++ms) red[w][lm + 16*ms] = colsum[ms];
  }
  __syncthreads();
  if (tid < 64) {
    float sden = 0.f;
    #pragma unroll
    for (int r2 = 0; r2 < 8; ++r2) sden += red[r2][tid];
    dsh[tid] = sden;
  }
  __syncthreads();

  // ---- epilogue: out = gamma*O/denom + x ----
  const float gam = gamma[0];
  float inv[4];
  #pragma unroll
  for (int ms = 0; ms < 4; ++ms) inv[ms] = gam / dsh[lm + 16*ms];

  #pragma unroll
  for (int cs = 0; cs < 2; ++cs)
    #pragma unroll
    for (int ms = 0; ms < 4; ++ms)
      #pragma unroll
      for (int r = 0; r < 4; ++r) {
        const int c = c0 + cs*16 + g*4 + r;
        const int m = m0 + 16*ms + lm;
        const size_t idx = ((size_t)b*C_ + c)*N_ + m;
        out[idx] = acc[cs][ms][r] * inv[ms] + x[idx];
      }
}

extern "C" void kernel_launch(void* const* d_in, const int* in_sizes, int n_in,
                              void* d_out, int out_size, void* d_ws, size_t ws_size,
                              hipStream_t stream) {
  const float* x     = (const float*)d_in[0];
  const float* Wq    = (const float*)d_in[1];
  const float* bq    = (const float*)d_in[2];
  const float* Wk    = (const float*)d_in[3];
  const float* bk    = (const float*)d_in[4];
  const float* Wv    = (const float*)d_in[5];
  const float* bv    = (const float*)d_in[6];
  const float* gamma = (const float*)d_in[7];
  float* out = (float*)d_out;
  bf16* ws   = (bf16*)d_ws;

  if (ws_size < WS_BYTES) return;   // ~37.9 MB scratch

  prep_w<<<320, 256, 0, stream>>>(Wq, bq, Wk, bk, Wv, bv, ws);
  prep_x<<<dim3(64, 8, 8), 256, 0, stream>>>(x, ws);
  qkv_mfma<<<dim3(64, 8), 256, 0, stream>>>(ws, ws);
  attn_kernel<<<512, 512, 0, stream>>>(ws, x, gamma, out);
}